// Round 5
// baseline (545.076 us; speedup 1.0000x reference)
//
#include <hip/hip_runtime.h>
#include <hip/hip_bf16.h>

#define D_   256
#define NH_  8
#define NL_  4
#define NP_  4
#define DFF_ 1024
#define BS_  8
#define NQ_  300
#define DH_  32
#define S_TOT 19947
#define EPS_ 1e-5f

typedef __bf16 bf16x8 __attribute__((ext_vector_type(8)));
typedef __bf16 bf16x4 __attribute__((ext_vector_type(4)));
typedef float  f32x4  __attribute__((ext_vector_type(4)));

// weight segment offsets in the bf16 weight workspace (elements)
#define W_INW  0
#define W_OUTW 196608
#define W_SOW  262144
#define W_AWW  327680
#define W_VW   360448
#define W_OPW  425984
#define W_L1W  491520
#define W_L2W  753664
#define W_TOT  1015808

// ---------------------------------------------------------------------------
__global__ __launch_bounds__(256) void cast_w_kernel(
    const float* __restrict__ s_inw, const float* __restrict__ s_outw,
    const float* __restrict__ s_sow, const float* __restrict__ s_aww,
    const float* __restrict__ s_vw,  const float* __restrict__ s_opw,
    const float* __restrict__ s_l1w, const float* __restrict__ s_l2w,
    __bf16* __restrict__ dst)
{
    const int i = (blockIdx.x * 256 + threadIdx.x) * 4;
    if (i >= W_TOT) return;
    const float* s; int off;
    if      (i < W_OUTW) { s = s_inw;  off = W_INW;  }
    else if (i < W_SOW)  { s = s_outw; off = W_OUTW; }
    else if (i < W_AWW)  { s = s_sow;  off = W_SOW;  }
    else if (i < W_VW)   { s = s_aww;  off = W_AWW;  }
    else if (i < W_OPW)  { s = s_vw;   off = W_VW;   }
    else if (i < W_L1W)  { s = s_opw;  off = W_OPW;  }
    else if (i < W_L2W)  { s = s_l1w;  off = W_L1W;  }
    else                 { s = s_l2w;  off = W_L2W;  }
    const float4 v = *(const float4*)(s + (i - off));
    bf16x4 o;
    o[0] = (__bf16)v.x; o[1] = (__bf16)v.y;
    o[2] = (__bf16)v.z; o[3] = (__bf16)v.w;
    *(bf16x4*)(dst + i) = o;
}

// ---------------------------------------------------------------------------
// Rearrange value weight (256x256 bf16, row-major [n][k]) into MFMA B-frag
// order: Wf[((s*16 + t)*64 + lane)*8 + e] = W[t*16 + (lane&15)][s*32 + (lane>>4)*8 + e]
// ---------------------------------------------------------------------------
__global__ __launch_bounds__(256) void rearrange_vw_kernel(
    const __bf16* __restrict__ W, __bf16* __restrict__ Wf)
{
    const int g = blockIdx.x * 256 + threadIdx.x;   // 0..8191
    const int l = g & 63;
    const int t = (g >> 6) & 15;
    const int s = g >> 10;
    const int row = t * 16 + (l & 15);
    const int col = s * 32 + (l >> 4) * 8;
    *(bf16x8*)(Wf + (size_t)g * 8) = *(const bf16x8*)(W + (size_t)row * 256 + col);
}

// ---------------------------------------------------------------------------
// Value GEMM v2: C[M,256](bf16) = A[M,256](fp32) @ W^T + bias.
// NO LDS, NO BARRIERS: each wave owns 32 rows x 64 cols; A frags loaded
// per-lane in native MFMA A-layout (fp32 -> bf16 in VALU), B frags from
// L2-resident frag-ordered Wf. Fully unrolled K -> deep load pipelining.
// Grid (4, ceil(M/128)): nh fastest so same-row blocks share A via L2/L3.
// ---------------------------------------------------------------------------
__global__ __launch_bounds__(256) void gemm_value(
    const float* __restrict__ A, const __bf16* __restrict__ Wf,
    const float* __restrict__ bias, __hip_bfloat16* __restrict__ C, int M)
{
    const int tid = threadIdx.x;
    const int wave = tid >> 6, lane = tid & 63;
    const int nh = blockIdx.x;                 // 64-col group
    const int m0 = blockIdx.y * 128 + wave * 32;
    const int frow = lane & 15;
    const int k8 = (lane >> 4) * 8;

    f32x4 acc[2][4];
#pragma unroll
    for (int i = 0; i < 2; ++i)
#pragma unroll
        for (int j = 0; j < 4; ++j) acc[i][j] = (f32x4){0.f, 0.f, 0.f, 0.f};

    // A frag pointers (clamp row; garbage rows masked at store)
    const int r0 = m0 + frow;       const int r1 = m0 + 16 + frow;
    const float* ap0 = A + (size_t)(r0 < M ? r0 : M - 1) * 256 + k8;
    const float* ap1 = A + (size_t)(r1 < M ? r1 : M - 1) * 256 + k8;
    const __bf16* bbase = Wf + ((size_t)(nh * 4) * 64 + lane) * 8;

#pragma unroll
    for (int s = 0; s < 8; ++s) {
        const float4 a00 = *(const float4*)(ap0 + s * 32);
        const float4 a01 = *(const float4*)(ap0 + s * 32 + 4);
        const float4 a10 = *(const float4*)(ap1 + s * 32);
        const float4 a11 = *(const float4*)(ap1 + s * 32 + 4);
        bf16x8 bF[4];
        const __bf16* bp = bbase + (size_t)s * 16 * 64 * 8;
#pragma unroll
        for (int j = 0; j < 4; ++j)
            bF[j] = *(const bf16x8*)(bp + j * 512);

        bf16x8 aF0, aF1;
        aF0[0] = (__bf16)a00.x; aF0[1] = (__bf16)a00.y;
        aF0[2] = (__bf16)a00.z; aF0[3] = (__bf16)a00.w;
        aF0[4] = (__bf16)a01.x; aF0[5] = (__bf16)a01.y;
        aF0[6] = (__bf16)a01.z; aF0[7] = (__bf16)a01.w;
        aF1[0] = (__bf16)a10.x; aF1[1] = (__bf16)a10.y;
        aF1[2] = (__bf16)a10.z; aF1[3] = (__bf16)a10.w;
        aF1[4] = (__bf16)a11.x; aF1[5] = (__bf16)a11.y;
        aF1[6] = (__bf16)a11.z; aF1[7] = (__bf16)a11.w;

#pragma unroll
        for (int j = 0; j < 4; ++j) {
            acc[0][j] = __builtin_amdgcn_mfma_f32_16x16x32_bf16(aF0, bF[j], acc[0][j], 0, 0, 0);
            acc[1][j] = __builtin_amdgcn_mfma_f32_16x16x32_bf16(aF1, bF[j], acc[1][j], 0, 0, 0);
        }
    }

#pragma unroll
    for (int i = 0; i < 2; ++i) {
        const int row = m0 + i * 16 + (lane >> 4) * 4;
#pragma unroll
        for (int j = 0; j < 4; ++j) {
            const int col = nh * 64 + j * 16 + frow;
            const float bb = bias[col];
#pragma unroll
            for (int r = 0; r < 4; ++r)
                if (row + r < M)
                    C[(size_t)(row + r) * 256 + col] = __float2bfloat16(acc[i][j][r] + bb);
        }
    }
}

// ---------------------------------------------------------------------------
// Small-M GEMM: C[M,N](f32) = (A (+A2))[M,K](fp32) @ W[N,K](bf16)^T + bias.
// ---------------------------------------------------------------------------
__global__ __launch_bounds__(256) void gemm_small(
    const float* __restrict__ A, const float* __restrict__ A2,
    const __bf16* __restrict__ W, const float* __restrict__ bias,
    float* __restrict__ C, int M, int N, int K, int relu)
{
    __shared__ __align__(16) __bf16 As[64][40];
    __shared__ __align__(16) __bf16 Bs[64][40];
    const int tid = threadIdx.x;
    const int wave = tid >> 6, lane = tid & 63;
    const int m0 = blockIdx.x * 64, n0 = blockIdx.y * 64;
    const int frow = lane & 15, fk = (lane >> 4) * 8;

    f32x4 acc[4];
#pragma unroll
    for (int j = 0; j < 4; ++j) acc[j] = (f32x4){0.f, 0.f, 0.f, 0.f};

    const int ar = tid >> 2;
    const int ak = (tid & 3) * 8;
    const bool a_ok = (m0 + ar) < M;

    for (int k0 = 0; k0 < K; k0 += 32) {
        float4 a0 = make_float4(0,0,0,0), a1 = a0;
        if (a_ok) {
            const float* ap = A + (size_t)(m0 + ar) * K + k0 + ak;
            a0 = *(const float4*)ap;
            a1 = *(const float4*)(ap + 4);
            if (A2) {
                const float* ap2 = A2 + (size_t)(m0 + ar) * K + k0 + ak;
                const float4 c0 = *(const float4*)ap2;
                const float4 c1 = *(const float4*)(ap2 + 4);
                a0.x += c0.x; a0.y += c0.y; a0.z += c0.z; a0.w += c0.w;
                a1.x += c1.x; a1.y += c1.y; a1.z += c1.z; a1.w += c1.w;
            }
        }
        const bf16x8 b8 = *(const bf16x8*)(W + (size_t)(n0 + ar) * K + k0 + ak);

        __syncthreads();
        bf16x8 w0;
        w0[0] = (__bf16)a0.x; w0[1] = (__bf16)a0.y; w0[2] = (__bf16)a0.z; w0[3] = (__bf16)a0.w;
        w0[4] = (__bf16)a1.x; w0[5] = (__bf16)a1.y; w0[6] = (__bf16)a1.z; w0[7] = (__bf16)a1.w;
        *(bf16x8*)&As[ar][ak] = w0;
        *(bf16x8*)&Bs[ar][ak] = b8;
        __syncthreads();

        const bf16x8 aF = *(const bf16x8*)&As[wave * 16 + frow][fk];
#pragma unroll
        for (int j = 0; j < 4; ++j) {
            const bf16x8 bF = *(const bf16x8*)&Bs[j * 16 + frow][fk];
            acc[j] = __builtin_amdgcn_mfma_f32_16x16x32_bf16(aF, bF, acc[j], 0, 0, 0);
        }
    }

    const int row = m0 + wave * 16 + (lane >> 4) * 4;
#pragma unroll
    for (int j = 0; j < 4; ++j) {
        const int col = n0 + j * 16 + frow;
        const float bb = bias[col];
#pragma unroll
        for (int r = 0; r < 4; ++r) {
            if (row + r >= M) continue;
            float val = acc[j][r] + bb;
            if (relu) val = fmaxf(val, 0.f);
            C[(size_t)(row + r) * N + col] = val;
        }
    }
}

// ---------------------------------------------------------------------------
// Self-attention stage 1+2: logits + in-register softmax -> P (bf16 probs).
// ---------------------------------------------------------------------------
__global__ __launch_bounds__(256) void attn_logits_kernel(
    const float* __restrict__ qk, __bf16* __restrict__ P)
{
    const int qt = blockIdx.x, bh = blockIdx.y;
    const int b = bh >> 3, h = bh & 7;
    const int wave = threadIdx.x >> 6, lane = threadIdx.x & 63;
    const int m = qt * 64 + wave * 16 + (lane & 15);
    const int k8 = (lane >> 4) * 8;
    const float scale = 0.17677669529663687f;   // 1/sqrt(32)

    bf16x8 aF = {};
    if (m < NQ_) {
        const float* qp = qk + (size_t)(b * NQ_ + m) * 512 + h * 32 + k8;
        const float4 q0 = *(const float4*)qp;
        const float4 q1 = *(const float4*)(qp + 4);
        aF[0] = (__bf16)q0.x; aF[1] = (__bf16)q0.y;
        aF[2] = (__bf16)q0.z; aF[3] = (__bf16)q0.w;
        aF[4] = (__bf16)q1.x; aF[5] = (__bf16)q1.y;
        aF[6] = (__bf16)q1.z; aF[7] = (__bf16)q1.w;
    }

    f32x4 c[19];
#pragma unroll
    for (int t = 0; t < 19; ++t) {
        const int n = t * 16 + (lane & 15);
        bf16x8 bF = {};
        if (n < NQ_) {
            const float* kp = qk + (size_t)(b * NQ_ + n) * 512 + 256 + h * 32 + k8;
            const float4 k0 = *(const float4*)kp;
            const float4 k1 = *(const float4*)(kp + 4);
            bF[0] = (__bf16)k0.x; bF[1] = (__bf16)k0.y;
            bF[2] = (__bf16)k0.z; bF[3] = (__bf16)k0.w;
            bF[4] = (__bf16)k1.x; bF[5] = (__bf16)k1.y;
            bF[6] = (__bf16)k1.z; bF[7] = (__bf16)k1.w;
        }
        f32x4 z = (f32x4){0.f, 0.f, 0.f, 0.f};
        c[t] = __builtin_amdgcn_mfma_f32_16x16x32_bf16(aF, bF, z, 0, 0, 0);
    }

    const int myc = lane & 15;
#pragma unroll
    for (int t = 0; t < 19; ++t) {
        const bool ok = (t * 16 + myc) < NQ_;
#pragma unroll
        for (int r = 0; r < 4; ++r)
            c[t][r] = ok ? c[t][r] * scale : -1e30f;
    }

    float mx[4] = {-1e30f, -1e30f, -1e30f, -1e30f};
#pragma unroll
    for (int t = 0; t < 19; ++t)
#pragma unroll
        for (int r = 0; r < 4; ++r) mx[r] = fmaxf(mx[r], c[t][r]);
#pragma unroll
    for (int off = 8; off; off >>= 1)
#pragma unroll
        for (int r = 0; r < 4; ++r)
            mx[r] = fmaxf(mx[r], __shfl_xor(mx[r], off, 64));

    float sum[4] = {0.f, 0.f, 0.f, 0.f};
#pragma unroll
    for (int t = 0; t < 19; ++t)
#pragma unroll
        for (int r = 0; r < 4; ++r) {
            const float e = __expf(c[t][r] - mx[r]);
            c[t][r] = e;
            sum[r] += e;
        }
#pragma unroll
    for (int off = 8; off; off >>= 1)
#pragma unroll
        for (int r = 0; r < 4; ++r)
            sum[r] += __shfl_xor(sum[r], off, 64);
    float inv[4];
#pragma unroll
    for (int r = 0; r < 4; ++r) inv[r] = 1.f / sum[r];

    __bf16* Pr = P + (size_t)bh * NQ_ * 320;
    const int row0 = qt * 64 + wave * 16 + (lane >> 4) * 4;
#pragma unroll
    for (int t = 0; t < 19; ++t) {
        const int col = t * 16 + myc;
        if (col >= NQ_) continue;
#pragma unroll
        for (int r = 0; r < 4; ++r)
            if (row0 + r < NQ_)
                Pr[(size_t)(row0 + r) * 320 + col] = (__bf16)(c[t][r] * inv[r]);
    }
}

// ---------------------------------------------------------------------------
// Stage 3: O = P @ V per (b,h). V^T staged bf16 in LDS (zero-padded to 320).
// ---------------------------------------------------------------------------
__global__ __launch_bounds__(256) void attn_pv_kernel(
    const __bf16* __restrict__ P, const float* __restrict__ v,
    float* __restrict__ attn)
{
    __shared__ __align__(16) __bf16 Vt[32][328];
    const int qt = blockIdx.x, bh = blockIdx.y;
    const int b = bh >> 3, h = bh & 7;
    const int tid = threadIdx.x;

    {
        const int d = tid & 31;
        for (int kk = tid >> 5; kk < NQ_; kk += 8)
            Vt[d][kk] = (__bf16)v[(size_t)(b * NQ_ + kk) * 256 + h * 32 + d];
        for (int i = tid; i < 32 * 20; i += 256)
            Vt[i & 31][300 + (i >> 5)] = (__bf16)0.f;
    }
    __syncthreads();

    const int wave = tid >> 6, lane = tid & 63;
    const int mrow = qt * 64 + wave * 16 + (lane & 15);
    const int k8 = (lane >> 4) * 8;
    const __bf16* Pr = P + (size_t)bh * NQ_ * 320;

    f32x4 acc0 = (f32x4){0.f, 0.f, 0.f, 0.f};
    f32x4 acc1 = acc0;
#pragma unroll
    for (int k0 = 0; k0 < 320; k0 += 32) {
        bf16x8 aF = {};
        if (mrow < NQ_) aF = *(const bf16x8*)(Pr + (size_t)mrow * 320 + k0 + k8);
        const bf16x8 b0 = *(const bf16x8*)&Vt[lane & 15][k0 + k8];
        const bf16x8 b1 = *(const bf16x8*)&Vt[16 + (lane & 15)][k0 + k8];
        acc0 = __builtin_amdgcn_mfma_f32_16x16x32_bf16(aF, b0, acc0, 0, 0, 0);
        acc1 = __builtin_amdgcn_mfma_f32_16x16x32_bf16(aF, b1, acc1, 0, 0, 0);
    }

    const int row0 = qt * 64 + wave * 16 + (lane >> 4) * 4;
    const int col = lane & 15;
#pragma unroll
    for (int r = 0; r < 4; ++r) {
        if (row0 + r >= NQ_) continue;
        float* op = attn + (size_t)(b * NQ_ + row0 + r) * 256 + h * 32;
        op[col]      = acc0[r];
        op[col + 16] = acc1[r];
    }
}

// ---------------------------------------------------------------------------
__global__ __launch_bounds__(256) void ln_kernel(
    const float* __restrict__ x, const float* __restrict__ res,
    const float* __restrict__ g, const float* __restrict__ bt,
    float* __restrict__ out,
    const float* __restrict__ pos, float* __restrict__ out2)
{
    const int row = blockIdx.x;
    const int tid = threadIdx.x;
    const size_t idx = (size_t)row * D_ + tid;
    float v = x[idx] + (res ? res[idx] : 0.f);

    __shared__ float red[4];
    float s = v;
#pragma unroll
    for (int off = 32; off; off >>= 1) s += __shfl_xor(s, off, 64);
    if ((tid & 63) == 0) red[tid >> 6] = s;
    __syncthreads();
    const float mean = (red[0] + red[1] + red[2] + red[3]) * (1.f / D_);
    const float c = v - mean;
    __syncthreads();

    float s2 = c * c;
#pragma unroll
    for (int off = 32; off; off >>= 1) s2 += __shfl_xor(s2, off, 64);
    if ((tid & 63) == 0) red[tid >> 6] = s2;
    __syncthreads();
    const float var = (red[0] + red[1] + red[2] + red[3]) * (1.f / D_);

    const float y = c * rsqrtf(var + EPS_) * g[tid] + bt[tid];
    out[idx] = y;
    if (out2) out2[idx] = y + pos[idx];
}

// ---------------------------------------------------------------------------
__global__ __launch_bounds__(256) void msdeform_kernel(
    const float* __restrict__ offs, const float* __restrict__ awl,
    const float* __restrict__ refp, const __hip_bfloat16* __restrict__ value,
    float* __restrict__ samp)
{
    const int row = blockIdx.x;
    const int b = row / NQ_;
    const int tid = threadIdx.x;
    const int h = tid >> 5, d = tid & 31;

    __shared__ float off_s[256];
    __shared__ float aw_s[128];
    __shared__ float ref_s[8];
    off_s[tid] = offs[(size_t)row * 256 + tid];
    if (tid < 128) aw_s[tid] = awl[(size_t)row * 128 + tid];
    if (tid < 8) ref_s[tid] = refp[(size_t)row * 8 + tid];
    __syncthreads();

    float mx = -1e30f;
#pragma unroll
    for (int i = 0; i < 16; ++i) mx = fmaxf(mx, aw_s[h * 16 + i]);
    float sum = 0.f;
#pragma unroll
    for (int i = 0; i < 16; ++i) sum += __expf(aw_s[h * 16 + i] - mx);
    const float winv = 1.f / sum;

    const int Hs[4] = {100, 50, 25, 13};
    const int Wl_[4] = {150, 75, 38, 19};
    const int S0[4] = {0, 15000, 18750, 19700};

    float o = 0.f;
    const __hip_bfloat16* vbase = value + ((size_t)b * S_TOT) * D_ + h * 32 + d;

#pragma unroll
    for (int l = 0; l < NL_; ++l) {
        const int Hl = Hs[l], Wl = Wl_[l];
        const float rx = ref_s[l * 2], ry = ref_s[l * 2 + 1];
        const __hip_bfloat16* vl = vbase + (size_t)S0[l] * D_;
#pragma unroll
        for (int p = 0; p < NP_; ++p) {
            const int oi = ((h * NL_ + l) * NP_ + p) * 2;
            const float lx = rx + off_s[oi] / (float)Wl;
            const float ly = ry + off_s[oi + 1] / (float)Hl;
            const float x = lx * Wl - 0.5f;
            const float y = ly * Hl - 0.5f;
            const float x0f = floorf(x), y0f = floorf(y);
            const float tx = x - x0f, ty = y - y0f;
            const int x0 = (int)x0f, y0 = (int)y0f;
            const float aw = __expf(aw_s[h * 16 + l * 4 + p] - mx) * winv;

            float sacc = 0.f;
#pragma unroll
            for (int cc = 0; cc < 4; ++cc) {
                const int dy = cc >> 1, dx = cc & 1;
                const int xi = x0 + dx, yi = y0 + dy;
                const float w = (dy ? ty : 1.f - ty) * (dx ? tx : 1.f - tx);
                if (xi >= 0 && xi < Wl && yi >= 0 && yi < Hl) {
                    const int idx = yi * Wl + xi;
                    sacc += w * __bfloat162float(vl[(size_t)idx * D_]);
                }
            }
            o += aw * sacc;
        }
    }
    samp[(size_t)row * 256 + tid] = o;
}

// ---------------------------------------------------------------------------
extern "C" void kernel_launch(void* const* d_in, const int* in_sizes, int n_in,
                              void* d_out, int out_size, void* d_ws, size_t ws_size,
                              hipStream_t stream)
{
    const float* tgt   = (const float*)d_in[0];
    const float* pos   = (const float*)d_in[1];
    const float* refp  = (const float*)d_in[2];
    const float* memory= (const float*)d_in[3];
    const float* in_w  = (const float*)d_in[7];
    const float* in_b  = (const float*)d_in[8];
    const float* outw  = (const float*)d_in[9];
    const float* outb  = (const float*)d_in[10];
    const float* n1g = (const float*)d_in[11]; const float* n1b = (const float*)d_in[12];
    const float* n2g = (const float*)d_in[13]; const float* n2b = (const float*)d_in[14];
    const float* n3g = (const float*)d_in[15]; const float* n3b = (const float*)d_in[16];
    const float* sow = (const float*)d_in[17]; const float* sob = (const float*)d_in[18];
    const float* aww = (const float*)d_in[19]; const float* awb = (const float*)d_in[20];
    const float* vw  = (const float*)d_in[21]; const float* vb_ = (const float*)d_in[22];
    const float* opw = (const float*)d_in[23]; const float* opb = (const float*)d_in[24];
    const float* l1w = (const float*)d_in[25]; const float* l1b = (const float*)d_in[26];
    const float* l2w = (const float*)d_in[27]; const float* l2b = (const float*)d_in[28];
    float* out = (float*)d_out;

    char* ws = (char*)d_ws;
    size_t o = 0;
    auto alloc = [&](size_t bytes) -> char* {
        char* p = ws + o;
        o += (bytes + 255) & ~(size_t)255;
        return p;
    };

    const int M = BS_ * NQ_;  // 2400
    __bf16* Wb = (__bf16*)alloc((size_t)W_TOT * 2);
    __bf16* Wf = (__bf16*)alloc((size_t)65536 * 2);
    __hip_bfloat16* value = (__hip_bfloat16*)alloc((size_t)BS_ * S_TOT * D_ * 2);
    __bf16* P    = (__bf16*)alloc((size_t)64 * NQ_ * 320 * 2);
    float* qk    = (float*)alloc((size_t)M * 512 * 4);
    float* v     = (float*)alloc((size_t)M * 256 * 4);
    float* attn  = (float*)alloc((size_t)M * 256 * 4);
    float* attno = (float*)alloc((size_t)M * 256 * 4);
    float* tgt1  = (float*)alloc((size_t)M * 256 * 4);
    float* query2= (float*)alloc((size_t)M * 256 * 4);
    float* offs  = (float*)alloc((size_t)M * 256 * 4);
    float* awl   = (float*)alloc((size_t)M * 128 * 4);
    float* samp  = (float*)alloc((size_t)M * 256 * 4);
    float* t2m   = (float*)alloc((size_t)M * 256 * 4);
    float* tgt2  = (float*)alloc((size_t)M * 256 * 4);
    float* ffn1  = (float*)alloc((size_t)M * 1024 * 4);
    float* ffn2  = (float*)alloc((size_t)M * 256 * 4);

    const dim3 blk(256);
    const int MB = (M + 63) / 64;                 // 38
    const int MV128 = (BS_ * S_TOT + 127) / 128;  // 1247

    cast_w_kernel<<<(W_TOT / 4 + 255) / 256, blk, 0, stream>>>(
        in_w, outw, sow, aww, vw, opw, l1w, l2w, Wb);
    rearrange_vw_kernel<<<32, blk, 0, stream>>>(Wb + W_VW, Wf);

    // --- self attention ---
    gemm_small<<<dim3(MB, 8), blk, 0, stream>>>(tgt, pos, Wb + W_INW, in_b, qk, M, 512, 256, 0);
    gemm_small<<<dim3(MB, 4), blk, 0, stream>>>(tgt, nullptr, Wb + W_INW + 512 * 256, in_b + 512, v, M, 256, 256, 0);
    attn_logits_kernel<<<dim3(5, 64), blk, 0, stream>>>(qk, P);
    attn_pv_kernel<<<dim3(5, 64), blk, 0, stream>>>(P, v, attn);
    gemm_small<<<dim3(MB, 4), blk, 0, stream>>>(attn, nullptr, Wb + W_OUTW, outb, attno, M, 256, 256, 0);
    ln_kernel<<<M, blk, 0, stream>>>(tgt, attno, n2g, n2b, tgt1, pos, query2);

    // --- ms-deformable attention ---
    gemm_small<<<dim3(MB, 4), blk, 0, stream>>>(query2, nullptr, Wb + W_SOW, sob, offs, M, 256, 256, 0);
    gemm_small<<<dim3(MB, 2), blk, 0, stream>>>(query2, nullptr, Wb + W_AWW, awb, awl, M, 128, 256, 0);
    gemm_value<<<dim3(4, MV128), blk, 0, stream>>>(memory, Wf, vb_, value, BS_ * S_TOT);
    msdeform_kernel<<<M, blk, 0, stream>>>(offs, awl, refp, value, samp);
    gemm_small<<<dim3(MB, 4), blk, 0, stream>>>(samp, nullptr, Wb + W_OPW, opb, t2m, M, 256, 256, 0);
    ln_kernel<<<M, blk, 0, stream>>>(tgt1, t2m, n1g, n1b, tgt2, nullptr, nullptr);

    // --- FFN ---
    gemm_small<<<dim3(MB, 16), blk, 0, stream>>>(tgt2, nullptr, Wb + W_L1W, l1b, ffn1, M, 1024, 256, 1);
    gemm_small<<<dim3(MB, 4), blk, 0, stream>>>(ffn1, nullptr, Wb + W_L2W, l2b, ffn2, M, 256, 1024, 0);
    ln_kernel<<<M, blk, 0, stream>>>(tgt2, ffn2, n3g, n3b, out, nullptr, nullptr);
}

// Round 6
// 543.016 us; speedup vs baseline: 1.0038x; 1.0038x over previous
//
#include <hip/hip_runtime.h>
#include <hip/hip_bf16.h>

#define D_   256
#define NH_  8
#define NL_  4
#define NP_  4
#define DFF_ 1024
#define BS_  8
#define NQ_  300
#define DH_  32
#define S_TOT 19947
#define EPS_ 1e-5f

typedef __bf16 bf16x8 __attribute__((ext_vector_type(8)));
typedef __bf16 bf16x4 __attribute__((ext_vector_type(4)));
typedef float  f32x4  __attribute__((ext_vector_type(4)));

// weight segment offsets in the bf16 weight workspace (elements)
#define W_INW  0
#define W_OUTW 196608
#define W_SOW  262144
#define W_AWW  327680
#define W_VW   360448
#define W_OPW  425984
#define W_L1W  491520
#define W_L2W  753664
#define W_TOT  1015808

// ---------------------------------------------------------------------------
__global__ __launch_bounds__(256) void cast_w_kernel(
    const float* __restrict__ s_inw, const float* __restrict__ s_outw,
    const float* __restrict__ s_sow, const float* __restrict__ s_aww,
    const float* __restrict__ s_vw,  const float* __restrict__ s_opw,
    const float* __restrict__ s_l1w, const float* __restrict__ s_l2w,
    __bf16* __restrict__ dst)
{
    const int i = (blockIdx.x * 256 + threadIdx.x) * 4;
    if (i >= W_TOT) return;
    const float* s; int off;
    if      (i < W_OUTW) { s = s_inw;  off = W_INW;  }
    else if (i < W_SOW)  { s = s_outw; off = W_OUTW; }
    else if (i < W_AWW)  { s = s_sow;  off = W_SOW;  }
    else if (i < W_VW)   { s = s_aww;  off = W_AWW;  }
    else if (i < W_OPW)  { s = s_vw;   off = W_VW;   }
    else if (i < W_L1W)  { s = s_opw;  off = W_OPW;  }
    else if (i < W_L2W)  { s = s_l1w;  off = W_L1W;  }
    else                 { s = s_l2w;  off = W_L2W;  }
    const float4 v = *(const float4*)(s + (i - off));
    bf16x4 o;
    o[0] = (__bf16)v.x; o[1] = (__bf16)v.y;
    o[2] = (__bf16)v.z; o[3] = (__bf16)v.w;
    *(bf16x4*)(dst + i) = o;
}

// ---------------------------------------------------------------------------
// Rearrange value weight (256x256 bf16, row-major [n][k]) into MFMA B-frag
// order: Wf[((s*16 + t)*64 + lane)*8 + e] = W[t*16 + (lane&15)][s*32 + (lane>>4)*8 + e]
// ---------------------------------------------------------------------------
__global__ __launch_bounds__(256) void rearrange_vw_kernel(
    const __bf16* __restrict__ W, __bf16* __restrict__ Wf)
{
    const int g = blockIdx.x * 256 + threadIdx.x;   // 0..8191
    const int l = g & 63;
    const int t = (g >> 6) & 15;
    const int s = g >> 10;
    const int row = t * 16 + (l & 15);
    const int col = s * 32 + (l >> 4) * 8;
    *(bf16x8*)(Wf + (size_t)g * 8) = *(const bf16x8*)(W + (size_t)row * 256 + col);
}

// ---------------------------------------------------------------------------
// Value GEMM v3: C[M,256](bf16) = A[M,256](fp32) @ W^T + bias.
// No LDS, no barriers. One block = 32 rows x 256 cols; the 4 waves split
// COLUMNS (wave = 64-col group) and issue IDENTICAL A-fragment loads, so A
// is fetched from HBM once per block (other 3 waves hit L1). B frags come
// from L2-resident frag-ordered Wf. Fully unrolled K.
// ---------------------------------------------------------------------------
__global__ __launch_bounds__(256) void gemm_value(
    const float* __restrict__ A, const __bf16* __restrict__ Wf,
    const float* __restrict__ bias, __hip_bfloat16* __restrict__ C, int M)
{
    const int tid = threadIdx.x;
    const int wave = tid >> 6, lane = tid & 63;   // wave = col group
    const int m0 = blockIdx.x * 32;
    const int frow = lane & 15;
    const int k8 = (lane >> 4) * 8;

    f32x4 acc[2][4];
#pragma unroll
    for (int i = 0; i < 2; ++i)
#pragma unroll
        for (int j = 0; j < 4; ++j) acc[i][j] = (f32x4){0.f, 0.f, 0.f, 0.f};

    const int r0 = m0 + frow;       const int r1 = m0 + 16 + frow;
    const float* ap0 = A + (size_t)(r0 < M ? r0 : M - 1) * 256 + k8;
    const float* ap1 = A + (size_t)(r1 < M ? r1 : M - 1) * 256 + k8;
    const __bf16* bbase = Wf + ((size_t)(wave * 4) * 64 + lane) * 8;

#pragma unroll
    for (int s = 0; s < 8; ++s) {
        const float4 a00 = *(const float4*)(ap0 + s * 32);
        const float4 a01 = *(const float4*)(ap0 + s * 32 + 4);
        const float4 a10 = *(const float4*)(ap1 + s * 32);
        const float4 a11 = *(const float4*)(ap1 + s * 32 + 4);
        bf16x8 bF[4];
        const __bf16* bp = bbase + (size_t)s * 16 * 64 * 8;
#pragma unroll
        for (int j = 0; j < 4; ++j)
            bF[j] = *(const bf16x8*)(bp + j * 512);

        bf16x8 aF0, aF1;
        aF0[0] = (__bf16)a00.x; aF0[1] = (__bf16)a00.y;
        aF0[2] = (__bf16)a00.z; aF0[3] = (__bf16)a00.w;
        aF0[4] = (__bf16)a01.x; aF0[5] = (__bf16)a01.y;
        aF0[6] = (__bf16)a01.z; aF0[7] = (__bf16)a01.w;
        aF1[0] = (__bf16)a10.x; aF1[1] = (__bf16)a10.y;
        aF1[2] = (__bf16)a10.z; aF1[3] = (__bf16)a10.w;
        aF1[4] = (__bf16)a11.x; aF1[5] = (__bf16)a11.y;
        aF1[6] = (__bf16)a11.z; aF1[7] = (__bf16)a11.w;

#pragma unroll
        for (int j = 0; j < 4; ++j) {
            acc[0][j] = __builtin_amdgcn_mfma_f32_16x16x32_bf16(aF0, bF[j], acc[0][j], 0, 0, 0);
            acc[1][j] = __builtin_amdgcn_mfma_f32_16x16x32_bf16(aF1, bF[j], acc[1][j], 0, 0, 0);
        }
    }

#pragma unroll
    for (int i = 0; i < 2; ++i) {
        const int row = m0 + i * 16 + (lane >> 4) * 4;
#pragma unroll
        for (int j = 0; j < 4; ++j) {
            const int col = wave * 64 + j * 16 + frow;
            const float bb = bias[col];
#pragma unroll
            for (int r = 0; r < 4; ++r)
                if (row + r < M)
                    C[(size_t)(row + r) * 256 + col] = __float2bfloat16(acc[i][j][r] + bb);
        }
    }
}

// ---------------------------------------------------------------------------
// Small-M GEMM: C[M,N](f32) = (A (+A2))[M,K](fp32) @ W[N,K](bf16)^T + bias.
// ---------------------------------------------------------------------------
__global__ __launch_bounds__(256) void gemm_small(
    const float* __restrict__ A, const float* __restrict__ A2,
    const __bf16* __restrict__ W, const float* __restrict__ bias,
    float* __restrict__ C, int M, int N, int K, int relu)
{
    __shared__ __align__(16) __bf16 As[64][40];
    __shared__ __align__(16) __bf16 Bs[64][40];
    const int tid = threadIdx.x;
    const int wave = tid >> 6, lane = tid & 63;
    const int m0 = blockIdx.x * 64, n0 = blockIdx.y * 64;
    const int frow = lane & 15, fk = (lane >> 4) * 8;

    f32x4 acc[4];
#pragma unroll
    for (int j = 0; j < 4; ++j) acc[j] = (f32x4){0.f, 0.f, 0.f, 0.f};

    const int ar = tid >> 2;
    const int ak = (tid & 3) * 8;
    const bool a_ok = (m0 + ar) < M;

    for (int k0 = 0; k0 < K; k0 += 32) {
        float4 a0 = make_float4(0,0,0,0), a1 = a0;
        if (a_ok) {
            const float* ap = A + (size_t)(m0 + ar) * K + k0 + ak;
            a0 = *(const float4*)ap;
            a1 = *(const float4*)(ap + 4);
            if (A2) {
                const float* ap2 = A2 + (size_t)(m0 + ar) * K + k0 + ak;
                const float4 c0 = *(const float4*)ap2;
                const float4 c1 = *(const float4*)(ap2 + 4);
                a0.x += c0.x; a0.y += c0.y; a0.z += c0.z; a0.w += c0.w;
                a1.x += c1.x; a1.y += c1.y; a1.z += c1.z; a1.w += c1.w;
            }
        }
        const bf16x8 b8 = *(const bf16x8*)(W + (size_t)(n0 + ar) * K + k0 + ak);

        __syncthreads();
        bf16x8 w0;
        w0[0] = (__bf16)a0.x; w0[1] = (__bf16)a0.y; w0[2] = (__bf16)a0.z; w0[3] = (__bf16)a0.w;
        w0[4] = (__bf16)a1.x; w0[5] = (__bf16)a1.y; w0[6] = (__bf16)a1.z; w0[7] = (__bf16)a1.w;
        *(bf16x8*)&As[ar][ak] = w0;
        *(bf16x8*)&Bs[ar][ak] = b8;
        __syncthreads();

        const bf16x8 aF = *(const bf16x8*)&As[wave * 16 + frow][fk];
#pragma unroll
        for (int j = 0; j < 4; ++j) {
            const bf16x8 bF = *(const bf16x8*)&Bs[j * 16 + frow][fk];
            acc[j] = __builtin_amdgcn_mfma_f32_16x16x32_bf16(aF, bF, acc[j], 0, 0, 0);
        }
    }

    const int row = m0 + wave * 16 + (lane >> 4) * 4;
#pragma unroll
    for (int j = 0; j < 4; ++j) {
        const int col = n0 + j * 16 + frow;
        const float bb = bias[col];
#pragma unroll
        for (int r = 0; r < 4; ++r) {
            if (row + r >= M) continue;
            float val = acc[j][r] + bb;
            if (relu) val = fmaxf(val, 0.f);
            C[(size_t)(row + r) * N + col] = val;
        }
    }
}

// ---------------------------------------------------------------------------
// Self-attention stage 1+2: logits + in-register softmax -> P (bf16 probs).
// ---------------------------------------------------------------------------
__global__ __launch_bounds__(256) void attn_logits_kernel(
    const float* __restrict__ qk, __bf16* __restrict__ P)
{
    const int qt = blockIdx.x, bh = blockIdx.y;
    const int b = bh >> 3, h = bh & 7;
    const int wave = threadIdx.x >> 6, lane = threadIdx.x & 63;
    const int m = qt * 64 + wave * 16 + (lane & 15);
    const int k8 = (lane >> 4) * 8;
    const float scale = 0.17677669529663687f;   // 1/sqrt(32)

    bf16x8 aF = {};
    if (m < NQ_) {
        const float* qp = qk + (size_t)(b * NQ_ + m) * 512 + h * 32 + k8;
        const float4 q0 = *(const float4*)qp;
        const float4 q1 = *(const float4*)(qp + 4);
        aF[0] = (__bf16)q0.x; aF[1] = (__bf16)q0.y;
        aF[2] = (__bf16)q0.z; aF[3] = (__bf16)q0.w;
        aF[4] = (__bf16)q1.x; aF[5] = (__bf16)q1.y;
        aF[6] = (__bf16)q1.z; aF[7] = (__bf16)q1.w;
    }

    f32x4 c[19];
#pragma unroll
    for (int t = 0; t < 19; ++t) {
        const int n = t * 16 + (lane & 15);
        bf16x8 bF = {};
        if (n < NQ_) {
            const float* kp = qk + (size_t)(b * NQ_ + n) * 512 + 256 + h * 32 + k8;
            const float4 k0 = *(const float4*)kp;
            const float4 k1 = *(const float4*)(kp + 4);
            bF[0] = (__bf16)k0.x; bF[1] = (__bf16)k0.y;
            bF[2] = (__bf16)k0.z; bF[3] = (__bf16)k0.w;
            bF[4] = (__bf16)k1.x; bF[5] = (__bf16)k1.y;
            bF[6] = (__bf16)k1.z; bF[7] = (__bf16)k1.w;
        }
        f32x4 z = (f32x4){0.f, 0.f, 0.f, 0.f};
        c[t] = __builtin_amdgcn_mfma_f32_16x16x32_bf16(aF, bF, z, 0, 0, 0);
    }

    const int myc = lane & 15;
#pragma unroll
    for (int t = 0; t < 19; ++t) {
        const bool ok = (t * 16 + myc) < NQ_;
#pragma unroll
        for (int r = 0; r < 4; ++r)
            c[t][r] = ok ? c[t][r] * scale : -1e30f;
    }

    float mx[4] = {-1e30f, -1e30f, -1e30f, -1e30f};
#pragma unroll
    for (int t = 0; t < 19; ++t)
#pragma unroll
        for (int r = 0; r < 4; ++r) mx[r] = fmaxf(mx[r], c[t][r]);
#pragma unroll
    for (int off = 8; off; off >>= 1)
#pragma unroll
        for (int r = 0; r < 4; ++r)
            mx[r] = fmaxf(mx[r], __shfl_xor(mx[r], off, 64));

    float sum[4] = {0.f, 0.f, 0.f, 0.f};
#pragma unroll
    for (int t = 0; t < 19; ++t)
#pragma unroll
        for (int r = 0; r < 4; ++r) {
            const float e = __expf(c[t][r] - mx[r]);
            c[t][r] = e;
            sum[r] += e;
        }
#pragma unroll
    for (int off = 8; off; off >>= 1)
#pragma unroll
        for (int r = 0; r < 4; ++r)
            sum[r] += __shfl_xor(sum[r], off, 64);
    float inv[4];
#pragma unroll
    for (int r = 0; r < 4; ++r) inv[r] = 1.f / sum[r];

    __bf16* Pr = P + (size_t)bh * NQ_ * 320;
    const int row0 = qt * 64 + wave * 16 + (lane >> 4) * 4;
#pragma unroll
    for (int t = 0; t < 19; ++t) {
        const int col = t * 16 + myc;
        if (col >= NQ_) continue;
#pragma unroll
        for (int r = 0; r < 4; ++r)
            if (row0 + r < NQ_)
                Pr[(size_t)(row0 + r) * 320 + col] = (__bf16)(c[t][r] * inv[r]);
    }
}

// ---------------------------------------------------------------------------
// Stage 3: O = P @ V per (b,h). V^T staged bf16 in LDS (zero-padded to 320).
// ---------------------------------------------------------------------------
__global__ __launch_bounds__(256) void attn_pv_kernel(
    const __bf16* __restrict__ P, const float* __restrict__ v,
    float* __restrict__ attn)
{
    __shared__ __align__(16) __bf16 Vt[32][328];
    const int qt = blockIdx.x, bh = blockIdx.y;
    const int b = bh >> 3, h = bh & 7;
    const int tid = threadIdx.x;

    {
        const int d = tid & 31;
        for (int kk = tid >> 5; kk < NQ_; kk += 8)
            Vt[d][kk] = (__bf16)v[(size_t)(b * NQ_ + kk) * 256 + h * 32 + d];
        for (int i = tid; i < 32 * 20; i += 256)
            Vt[i & 31][300 + (i >> 5)] = (__bf16)0.f;
    }
    __syncthreads();

    const int wave = tid >> 6, lane = tid & 63;
    const int mrow = qt * 64 + wave * 16 + (lane & 15);
    const int k8 = (lane >> 4) * 8;
    const __bf16* Pr = P + (size_t)bh * NQ_ * 320;

    f32x4 acc0 = (f32x4){0.f, 0.f, 0.f, 0.f};
    f32x4 acc1 = acc0;
#pragma unroll
    for (int k0 = 0; k0 < 320; k0 += 32) {
        bf16x8 aF = {};
        if (mrow < NQ_) aF = *(const bf16x8*)(Pr + (size_t)mrow * 320 + k0 + k8);
        const bf16x8 b0 = *(const bf16x8*)&Vt[lane & 15][k0 + k8];
        const bf16x8 b1 = *(const bf16x8*)&Vt[16 + (lane & 15)][k0 + k8];
        acc0 = __builtin_amdgcn_mfma_f32_16x16x32_bf16(aF, b0, acc0, 0, 0, 0);
        acc1 = __builtin_amdgcn_mfma_f32_16x16x32_bf16(aF, b1, acc1, 0, 0, 0);
    }

    const int row0 = qt * 64 + wave * 16 + (lane >> 4) * 4;
    const int col = lane & 15;
#pragma unroll
    for (int r = 0; r < 4; ++r) {
        if (row0 + r >= NQ_) continue;
        float* op = attn + (size_t)(b * NQ_ + row0 + r) * 256 + h * 32;
        op[col]      = acc0[r];
        op[col + 16] = acc1[r];
    }
}

// ---------------------------------------------------------------------------
__global__ __launch_bounds__(256) void ln_kernel(
    const float* __restrict__ x, const float* __restrict__ res,
    const float* __restrict__ g, const float* __restrict__ bt,
    float* __restrict__ out,
    const float* __restrict__ pos, float* __restrict__ out2)
{
    const int row = blockIdx.x;
    const int tid = threadIdx.x;
    const size_t idx = (size_t)row * D_ + tid;
    float v = x[idx] + (res ? res[idx] : 0.f);

    __shared__ float red[4];
    float s = v;
#pragma unroll
    for (int off = 32; off; off >>= 1) s += __shfl_xor(s, off, 64);
    if ((tid & 63) == 0) red[tid >> 6] = s;
    __syncthreads();
    const float mean = (red[0] + red[1] + red[2] + red[3]) * (1.f / D_);
    const float c = v - mean;
    __syncthreads();

    float s2 = c * c;
#pragma unroll
    for (int off = 32; off; off >>= 1) s2 += __shfl_xor(s2, off, 64);
    if ((tid & 63) == 0) red[tid >> 6] = s2;
    __syncthreads();
    const float var = (red[0] + red[1] + red[2] + red[3]) * (1.f / D_);

    const float y = c * rsqrtf(var + EPS_) * g[tid] + bt[tid];
    out[idx] = y;
    if (out2) out2[idx] = y + pos[idx];
}

// ---------------------------------------------------------------------------
__global__ __launch_bounds__(256) void msdeform_kernel(
    const float* __restrict__ offs, const float* __restrict__ awl,
    const float* __restrict__ refp, const __hip_bfloat16* __restrict__ value,
    float* __restrict__ samp)
{
    const int row = blockIdx.x;
    const int b = row / NQ_;
    const int tid = threadIdx.x;
    const int h = tid >> 5, d = tid & 31;

    __shared__ float off_s[256];
    __shared__ float aw_s[128];
    __shared__ float ref_s[8];
    off_s[tid] = offs[(size_t)row * 256 + tid];
    if (tid < 128) aw_s[tid] = awl[(size_t)row * 128 + tid];
    if (tid < 8) ref_s[tid] = refp[(size_t)row * 8 + tid];
    __syncthreads();

    float mx = -1e30f;
#pragma unroll
    for (int i = 0; i < 16; ++i) mx = fmaxf(mx, aw_s[h * 16 + i]);
    float sum = 0.f;
#pragma unroll
    for (int i = 0; i < 16; ++i) sum += __expf(aw_s[h * 16 + i] - mx);
    const float winv = 1.f / sum;

    const int Hs[4] = {100, 50, 25, 13};
    const int Wl_[4] = {150, 75, 38, 19};
    const int S0[4] = {0, 15000, 18750, 19700};

    float o = 0.f;
    const __hip_bfloat16* vbase = value + ((size_t)b * S_TOT) * D_ + h * 32 + d;

#pragma unroll
    for (int l = 0; l < NL_; ++l) {
        const int Hl = Hs[l], Wl = Wl_[l];
        const float rx = ref_s[l * 2], ry = ref_s[l * 2 + 1];
        const __hip_bfloat16* vl = vbase + (size_t)S0[l] * D_;
#pragma unroll
        for (int p = 0; p < NP_; ++p) {
            const int oi = ((h * NL_ + l) * NP_ + p) * 2;
            const float lx = rx + off_s[oi] / (float)Wl;
            const float ly = ry + off_s[oi + 1] / (float)Hl;
            const float x = lx * Wl - 0.5f;
            const float y = ly * Hl - 0.5f;
            const float x0f = floorf(x), y0f = floorf(y);
            const float tx = x - x0f, ty = y - y0f;
            const int x0 = (int)x0f, y0 = (int)y0f;
            const float aw = __expf(aw_s[h * 16 + l * 4 + p] - mx) * winv;

            float sacc = 0.f;
#pragma unroll
            for (int cc = 0; cc < 4; ++cc) {
                const int dy = cc >> 1, dx = cc & 1;
                const int xi = x0 + dx, yi = y0 + dy;
                const float w = (dy ? ty : 1.f - ty) * (dx ? tx : 1.f - tx);
                if (xi >= 0 && xi < Wl && yi >= 0 && yi < Hl) {
                    const int idx = yi * Wl + xi;
                    sacc += w * __bfloat162float(vl[(size_t)idx * D_]);
                }
            }
            o += aw * sacc;
        }
    }
    samp[(size_t)row * 256 + tid] = o;
}

// ---------------------------------------------------------------------------
extern "C" void kernel_launch(void* const* d_in, const int* in_sizes, int n_in,
                              void* d_out, int out_size, void* d_ws, size_t ws_size,
                              hipStream_t stream)
{
    const float* tgt   = (const float*)d_in[0];
    const float* pos   = (const float*)d_in[1];
    const float* refp  = (const float*)d_in[2];
    const float* memory= (const float*)d_in[3];
    const float* in_w  = (const float*)d_in[7];
    const float* in_b  = (const float*)d_in[8];
    const float* outw  = (const float*)d_in[9];
    const float* outb  = (const float*)d_in[10];
    const float* n1g = (const float*)d_in[11]; const float* n1b = (const float*)d_in[12];
    const float* n2g = (const float*)d_in[13]; const float* n2b = (const float*)d_in[14];
    const float* n3g = (const float*)d_in[15]; const float* n3b = (const float*)d_in[16];
    const float* sow = (const float*)d_in[17]; const float* sob = (const float*)d_in[18];
    const float* aww = (const float*)d_in[19]; const float* awb = (const float*)d_in[20];
    const float* vw  = (const float*)d_in[21]; const float* vb_ = (const float*)d_in[22];
    const float* opw = (const float*)d_in[23]; const float* opb = (const float*)d_in[24];
    const float* l1w = (const float*)d_in[25]; const float* l1b = (const float*)d_in[26];
    const float* l2w = (const float*)d_in[27]; const float* l2b = (const float*)d_in[28];
    float* out = (float*)d_out;

    char* ws = (char*)d_ws;
    size_t o = 0;
    auto alloc = [&](size_t bytes) -> char* {
        char* p = ws + o;
        o += (bytes + 255) & ~(size_t)255;
        return p;
    };

    const int M = BS_ * NQ_;  // 2400
    __bf16* Wb = (__bf16*)alloc((size_t)W_TOT * 2);
    __bf16* Wf = (__bf16*)alloc((size_t)65536 * 2);
    __hip_bfloat16* value = (__hip_bfloat16*)alloc((size_t)BS_ * S_TOT * D_ * 2);
    __bf16* P    = (__bf16*)alloc((size_t)64 * NQ_ * 320 * 2);
    float* qk    = (float*)alloc((size_t)M * 512 * 4);
    float* v     = (float*)alloc((size_t)M * 256 * 4);
    float* attn  = (float*)alloc((size_t)M * 256 * 4);
    float* attno = (float*)alloc((size_t)M * 256 * 4);
    float* tgt1  = (float*)alloc((size_t)M * 256 * 4);
    float* query2= (float*)alloc((size_t)M * 256 * 4);
    float* offs  = (float*)alloc((size_t)M * 256 * 4);
    float* awl   = (float*)alloc((size_t)M * 128 * 4);
    float* samp  = (float*)alloc((size_t)M * 256 * 4);
    float* t2m   = (float*)alloc((size_t)M * 256 * 4);
    float* tgt2  = (float*)alloc((size_t)M * 256 * 4);
    float* ffn1  = (float*)alloc((size_t)M * 1024 * 4);
    float* ffn2  = (float*)alloc((size_t)M * 256 * 4);

    const dim3 blk(256);
    const int MB = (M + 63) / 64;                 // 38
    const int MV32 = (BS_ * S_TOT + 31) / 32;     // 4987

    cast_w_kernel<<<(W_TOT / 4 + 255) / 256, blk, 0, stream>>>(
        in_w, outw, sow, aww, vw, opw, l1w, l2w, Wb);
    rearrange_vw_kernel<<<32, blk, 0, stream>>>(Wb + W_VW, Wf);

    // --- self attention ---
    gemm_small<<<dim3(MB, 8), blk, 0, stream>>>(tgt, pos, Wb + W_INW, in_b, qk, M, 512, 256, 0);
    gemm_small<<<dim3(MB, 4), blk, 0, stream>>>(tgt, nullptr, Wb + W_INW + 512 * 256, in_b + 512, v, M, 256, 256, 0);
    attn_logits_kernel<<<dim3(5, 64), blk, 0, stream>>>(qk, P);
    attn_pv_kernel<<<dim3(5, 64), blk, 0, stream>>>(P, v, attn);
    gemm_small<<<dim3(MB, 4), blk, 0, stream>>>(attn, nullptr, Wb + W_OUTW, outb, attno, M, 256, 256, 0);
    ln_kernel<<<M, blk, 0, stream>>>(tgt, attno, n2g, n2b, tgt1, pos, query2);

    // --- ms-deformable attention ---
    gemm_small<<<dim3(MB, 4), blk, 0, stream>>>(query2, nullptr, Wb + W_SOW, sob, offs, M, 256, 256, 0);
    gemm_small<<<dim3(MB, 2), blk, 0, stream>>>(query2, nullptr, Wb + W_AWW, awb, awl, M, 128, 256, 0);
    gemm_value<<<dim3(MV32), blk, 0, stream>>>(memory, Wf, vb_, value, BS_ * S_TOT);
    msdeform_kernel<<<M, blk, 0, stream>>>(offs, awl, refp, value, samp);
    gemm_small<<<dim3(MB, 4), blk, 0, stream>>>(samp, nullptr, Wb + W_OPW, opb, t2m, M, 256, 256, 0);
    ln_kernel<<<M, blk, 0, stream>>>(tgt1, t2m, n1g, n1b, tgt2, nullptr, nullptr);

    // --- FFN ---
    gemm_small<<<dim3(MB, 16), blk, 0, stream>>>(tgt2, nullptr, Wb + W_L1W, l1b, ffn1, M, 1024, 256, 1);
    gemm_small<<<dim3(MB, 4), blk, 0, stream>>>(ffn1, nullptr, Wb + W_L2W, l2b, ffn2, M, 256, 1024, 0);
    ln_kernel<<<M, blk, 0, stream>>>(tgt2, ffn2, n3g, n3b, out, nullptr, nullptr);
}

// Round 7
// 500.931 us; speedup vs baseline: 1.0881x; 1.0840x over previous
//
#include <hip/hip_runtime.h>
#include <hip/hip_bf16.h>

#define D_   256
#define NH_  8
#define NL_  4
#define NP_  4
#define DFF_ 1024
#define BS_  8
#define NQ_  300
#define DH_  32
#define S_TOT 19947
#define EPS_ 1e-5f

typedef __bf16 bf16x8 __attribute__((ext_vector_type(8)));
typedef __bf16 bf16x4 __attribute__((ext_vector_type(4)));
typedef float  f32x4  __attribute__((ext_vector_type(4)));

// weight segment offsets in the bf16 weight workspace (elements)
#define W_INW  0
#define W_OUTW 196608
#define W_SOW  262144
#define W_AWW  327680
#define W_VW   360448
#define W_OPW  425984
#define W_L1W  491520
#define W_L2W  753664
#define W_TOT  1015808

// ---------------------------------------------------------------------------
__global__ __launch_bounds__(256) void cast_w_kernel(
    const float* __restrict__ s_inw, const float* __restrict__ s_outw,
    const float* __restrict__ s_sow, const float* __restrict__ s_aww,
    const float* __restrict__ s_vw,  const float* __restrict__ s_opw,
    const float* __restrict__ s_l1w, const float* __restrict__ s_l2w,
    __bf16* __restrict__ dst)
{
    const int i = (blockIdx.x * 256 + threadIdx.x) * 4;
    if (i >= W_TOT) return;
    const float* s; int off;
    if      (i < W_OUTW) { s = s_inw;  off = W_INW;  }
    else if (i < W_SOW)  { s = s_outw; off = W_OUTW; }
    else if (i < W_AWW)  { s = s_sow;  off = W_SOW;  }
    else if (i < W_VW)   { s = s_aww;  off = W_AWW;  }
    else if (i < W_OPW)  { s = s_vw;   off = W_VW;   }
    else if (i < W_L1W)  { s = s_opw;  off = W_OPW;  }
    else if (i < W_L2W)  { s = s_l1w;  off = W_L1W;  }
    else                 { s = s_l2w;  off = W_L2W;  }
    const float4 v = *(const float4*)(s + (i - off));
    bf16x4 o;
    o[0] = (__bf16)v.x; o[1] = (__bf16)v.y;
    o[2] = (__bf16)v.z; o[3] = (__bf16)v.w;
    *(bf16x4*)(dst + i) = o;
}

// ---------------------------------------------------------------------------
// Rearrange value weight (256x256 bf16, row-major [n][k]) into MFMA B-frag
// order: Wf[((s*16 + t)*64 + lane)*8 + e] = W[t*16 + (lane&15)][s*32 + (lane>>4)*8 + e]
// ---------------------------------------------------------------------------
__global__ __launch_bounds__(256) void rearrange_vw_kernel(
    const __bf16* __restrict__ W, __bf16* __restrict__ Wf)
{
    const int g = blockIdx.x * 256 + threadIdx.x;   // 0..8191
    const int l = g & 63;
    const int t = (g >> 6) & 15;
    const int s = g >> 10;
    const int row = t * 16 + (l & 15);
    const int col = s * 32 + (l >> 4) * 8;
    *(bf16x8*)(Wf + (size_t)g * 8) = *(const bf16x8*)(W + (size_t)row * 256 + col);
}

// ---------------------------------------------------------------------------
// Value GEMM v4: C[M,256](bf16) = A[M,256](fp32) @ W^T + bias.
// Block = 32 rows x 256 cols; waves split columns. A tile (32 KB fp32)
// staged ONCE per block via global_load_lds (zero-VGPR async DMA, all 8
// row-stages per wave in flight), single barrier, then a barrier-free
// fully-unrolled K loop: A frags from LDS (stride 260 floats = aligned,
// bank-balanced), B frags from L2-resident frag-ordered Wf.
// ---------------------------------------------------------------------------
#define AROW 260   // floats per LDS row (256 + 4 pad): 16B-aligned, bank-balanced

__global__ __launch_bounds__(256, 4) void gemm_value(
    const float* __restrict__ A, const __bf16* __restrict__ Wf,
    const float* __restrict__ bias, __hip_bfloat16* __restrict__ C, int M)
{
    __shared__ __align__(16) float As[32 * AROW];
    const int tid = threadIdx.x;
    const int wave = tid >> 6, lane = tid & 63;   // wave = 64-col group
    const int m0 = blockIdx.x * 32;
    const int frow = lane & 15;
    const int k8 = (lane >> 4) * 8;

    // ---- stage 32 A rows (1 KB each) into LDS ----
#pragma unroll
    for (int i = 0; i < 8; ++i) {
        const int r = wave * 8 + i;
        int gr = m0 + r; if (gr >= M) gr = M - 1;
        const float* gsrc = A + (size_t)gr * 256 + lane * 4;   // lane*16 B
        float* ldst = &As[r * AROW];                            // wave-uniform base
#if __has_builtin(__builtin_amdgcn_global_load_lds)
        __builtin_amdgcn_global_load_lds(
            (const __attribute__((address_space(1))) void*)(const void*)gsrc,
            (__attribute__((address_space(3))) void*)(void*)ldst, 16, 0, 0);
#else
        *(float4*)(ldst + lane * 4) = *(const float4*)gsrc;
#endif
    }
    __syncthreads();

    f32x4 acc[2][4];
#pragma unroll
    for (int i = 0; i < 2; ++i)
#pragma unroll
        for (int j = 0; j < 4; ++j) acc[i][j] = (f32x4){0.f, 0.f, 0.f, 0.f};

    const __bf16* bbase = Wf + ((size_t)(wave * 4) * 64 + lane) * 8;

#pragma unroll
    for (int s = 0; s < 8; ++s) {
        // B frags: coalesced 1KB/wave reads from L2-resident Wf
        bf16x8 bF[4];
        const __bf16* bp = bbase + (size_t)s * 8192;
#pragma unroll
        for (int j = 0; j < 4; ++j)
            bF[j] = *(const bf16x8*)(bp + j * 512);

        // A frags from LDS (shared by all 4 waves)
        const float* a0p = &As[frow * AROW + s * 32 + k8];
        const float* a1p = &As[(16 + frow) * AROW + s * 32 + k8];
        const float4 a00 = *(const float4*)a0p;
        const float4 a01 = *(const float4*)(a0p + 4);
        const float4 a10 = *(const float4*)a1p;
        const float4 a11 = *(const float4*)(a1p + 4);

        bf16x8 aF0, aF1;
        aF0[0] = (__bf16)a00.x; aF0[1] = (__bf16)a00.y;
        aF0[2] = (__bf16)a00.z; aF0[3] = (__bf16)a00.w;
        aF0[4] = (__bf16)a01.x; aF0[5] = (__bf16)a01.y;
        aF0[6] = (__bf16)a01.z; aF0[7] = (__bf16)a01.w;
        aF1[0] = (__bf16)a10.x; aF1[1] = (__bf16)a10.y;
        aF1[2] = (__bf16)a10.z; aF1[3] = (__bf16)a10.w;
        aF1[4] = (__bf16)a11.x; aF1[5] = (__bf16)a11.y;
        aF1[6] = (__bf16)a11.z; aF1[7] = (__bf16)a11.w;

#pragma unroll
        for (int j = 0; j < 4; ++j) {
            acc[0][j] = __builtin_amdgcn_mfma_f32_16x16x32_bf16(aF0, bF[j], acc[0][j], 0, 0, 0);
            acc[1][j] = __builtin_amdgcn_mfma_f32_16x16x32_bf16(aF1, bF[j], acc[1][j], 0, 0, 0);
        }
    }

#pragma unroll
    for (int i = 0; i < 2; ++i) {
        const int row = m0 + i * 16 + (lane >> 4) * 4;
#pragma unroll
        for (int j = 0; j < 4; ++j) {
            const int col = wave * 64 + j * 16 + frow;
            const float bb = bias[col];
#pragma unroll
            for (int r = 0; r < 4; ++r)
                if (row + r < M)
                    C[(size_t)(row + r) * 256 + col] = __float2bfloat16(acc[i][j][r] + bb);
        }
    }
}

// ---------------------------------------------------------------------------
// Small-M GEMM: C[M,N](f32) = (A (+A2))[M,K](fp32) @ W[N,K](bf16)^T + bias.
// ---------------------------------------------------------------------------
__global__ __launch_bounds__(256) void gemm_small(
    const float* __restrict__ A, const float* __restrict__ A2,
    const __bf16* __restrict__ W, const float* __restrict__ bias,
    float* __restrict__ C, int M, int N, int K, int relu)
{
    __shared__ __align__(16) __bf16 As[64][40];
    __shared__ __align__(16) __bf16 Bs[64][40];
    const int tid = threadIdx.x;
    const int wave = tid >> 6, lane = tid & 63;
    const int m0 = blockIdx.x * 64, n0 = blockIdx.y * 64;
    const int frow = lane & 15, fk = (lane >> 4) * 8;

    f32x4 acc[4];
#pragma unroll
    for (int j = 0; j < 4; ++j) acc[j] = (f32x4){0.f, 0.f, 0.f, 0.f};

    const int ar = tid >> 2;
    const int ak = (tid & 3) * 8;
    const bool a_ok = (m0 + ar) < M;

    for (int k0 = 0; k0 < K; k0 += 32) {
        float4 a0 = make_float4(0,0,0,0), a1 = a0;
        if (a_ok) {
            const float* ap = A + (size_t)(m0 + ar) * K + k0 + ak;
            a0 = *(const float4*)ap;
            a1 = *(const float4*)(ap + 4);
            if (A2) {
                const float* ap2 = A2 + (size_t)(m0 + ar) * K + k0 + ak;
                const float4 c0 = *(const float4*)ap2;
                const float4 c1 = *(const float4*)(ap2 + 4);
                a0.x += c0.x; a0.y += c0.y; a0.z += c0.z; a0.w += c0.w;
                a1.x += c1.x; a1.y += c1.y; a1.z += c1.z; a1.w += c1.w;
            }
        }
        const bf16x8 b8 = *(const bf16x8*)(W + (size_t)(n0 + ar) * K + k0 + ak);

        __syncthreads();
        bf16x8 w0;
        w0[0] = (__bf16)a0.x; w0[1] = (__bf16)a0.y; w0[2] = (__bf16)a0.z; w0[3] = (__bf16)a0.w;
        w0[4] = (__bf16)a1.x; w0[5] = (__bf16)a1.y; w0[6] = (__bf16)a1.z; w0[7] = (__bf16)a1.w;
        *(bf16x8*)&As[ar][ak] = w0;
        *(bf16x8*)&Bs[ar][ak] = b8;
        __syncthreads();

        const bf16x8 aF = *(const bf16x8*)&As[wave * 16 + frow][fk];
#pragma unroll
        for (int j = 0; j < 4; ++j) {
            const bf16x8 bF = *(const bf16x8*)&Bs[j * 16 + frow][fk];
            acc[j] = __builtin_amdgcn_mfma_f32_16x16x32_bf16(aF, bF, acc[j], 0, 0, 0);
        }
    }

    const int row = m0 + wave * 16 + (lane >> 4) * 4;
#pragma unroll
    for (int j = 0; j < 4; ++j) {
        const int col = n0 + j * 16 + frow;
        const float bb = bias[col];
#pragma unroll
        for (int r = 0; r < 4; ++r) {
            if (row + r >= M) continue;
            float val = acc[j][r] + bb;
            if (relu) val = fmaxf(val, 0.f);
            C[(size_t)(row + r) * N + col] = val;
        }
    }
}

// ---------------------------------------------------------------------------
// Self-attention stage 1+2: logits + in-register softmax -> P (bf16 probs).
// ---------------------------------------------------------------------------
__global__ __launch_bounds__(256) void attn_logits_kernel(
    const float* __restrict__ qk, __bf16* __restrict__ P)
{
    const int qt = blockIdx.x, bh = blockIdx.y;
    const int b = bh >> 3, h = bh & 7;
    const int wave = threadIdx.x >> 6, lane = threadIdx.x & 63;
    const int m = qt * 64 + wave * 16 + (lane & 15);
    const int k8 = (lane >> 4) * 8;
    const float scale = 0.17677669529663687f;   // 1/sqrt(32)

    bf16x8 aF = {};
    if (m < NQ_) {
        const float* qp = qk + (size_t)(b * NQ_ + m) * 512 + h * 32 + k8;
        const float4 q0 = *(const float4*)qp;
        const float4 q1 = *(const float4*)(qp + 4);
        aF[0] = (__bf16)q0.x; aF[1] = (__bf16)q0.y;
        aF[2] = (__bf16)q0.z; aF[3] = (__bf16)q0.w;
        aF[4] = (__bf16)q1.x; aF[5] = (__bf16)q1.y;
        aF[6] = (__bf16)q1.z; aF[7] = (__bf16)q1.w;
    }

    f32x4 c[19];
#pragma unroll
    for (int t = 0; t < 19; ++t) {
        const int n = t * 16 + (lane & 15);
        bf16x8 bF = {};
        if (n < NQ_) {
            const float* kp = qk + (size_t)(b * NQ_ + n) * 512 + 256 + h * 32 + k8;
            const float4 k0 = *(const float4*)kp;
            const float4 k1 = *(const float4*)(kp + 4);
            bF[0] = (__bf16)k0.x; bF[1] = (__bf16)k0.y;
            bF[2] = (__bf16)k0.z; bF[3] = (__bf16)k0.w;
            bF[4] = (__bf16)k1.x; bF[5] = (__bf16)k1.y;
            bF[6] = (__bf16)k1.z; bF[7] = (__bf16)k1.w;
        }
        f32x4 z = (f32x4){0.f, 0.f, 0.f, 0.f};
        c[t] = __builtin_amdgcn_mfma_f32_16x16x32_bf16(aF, bF, z, 0, 0, 0);
    }

    const int myc = lane & 15;
#pragma unroll
    for (int t = 0; t < 19; ++t) {
        const bool ok = (t * 16 + myc) < NQ_;
#pragma unroll
        for (int r = 0; r < 4; ++r)
            c[t][r] = ok ? c[t][r] * scale : -1e30f;
    }

    float mx[4] = {-1e30f, -1e30f, -1e30f, -1e30f};
#pragma unroll
    for (int t = 0; t < 19; ++t)
#pragma unroll
        for (int r = 0; r < 4; ++r) mx[r] = fmaxf(mx[r], c[t][r]);
#pragma unroll
    for (int off = 8; off; off >>= 1)
#pragma unroll
        for (int r = 0; r < 4; ++r)
            mx[r] = fmaxf(mx[r], __shfl_xor(mx[r], off, 64));

    float sum[4] = {0.f, 0.f, 0.f, 0.f};
#pragma unroll
    for (int t = 0; t < 19; ++t)
#pragma unroll
        for (int r = 0; r < 4; ++r) {
            const float e = __expf(c[t][r] - mx[r]);
            c[t][r] = e;
            sum[r] += e;
        }
#pragma unroll
    for (int off = 8; off; off >>= 1)
#pragma unroll
        for (int r = 0; r < 4; ++r)
            sum[r] += __shfl_xor(sum[r], off, 64);
    float inv[4];
#pragma unroll
    for (int r = 0; r < 4; ++r) inv[r] = 1.f / sum[r];

    __bf16* Pr = P + (size_t)bh * NQ_ * 320;
    const int row0 = qt * 64 + wave * 16 + (lane >> 4) * 4;
#pragma unroll
    for (int t = 0; t < 19; ++t) {
        const int col = t * 16 + myc;
        if (col >= NQ_) continue;
#pragma unroll
        for (int r = 0; r < 4; ++r)
            if (row0 + r < NQ_)
                Pr[(size_t)(row0 + r) * 320 + col] = (__bf16)(c[t][r] * inv[r]);
    }
}

// ---------------------------------------------------------------------------
// Stage 3: O = P @ V per (b,h). V^T staged bf16 in LDS (zero-padded to 320).
// ---------------------------------------------------------------------------
__global__ __launch_bounds__(256) void attn_pv_kernel(
    const __bf16* __restrict__ P, const float* __restrict__ v,
    float* __restrict__ attn)
{
    __shared__ __align__(16) __bf16 Vt[32][328];
    const int qt = blockIdx.x, bh = blockIdx.y;
    const int b = bh >> 3, h = bh & 7;
    const int tid = threadIdx.x;

    {
        const int d = tid & 31;
        for (int kk = tid >> 5; kk < NQ_; kk += 8)
            Vt[d][kk] = (__bf16)v[(size_t)(b * NQ_ + kk) * 256 + h * 32 + d];
        for (int i = tid; i < 32 * 20; i += 256)
            Vt[i & 31][300 + (i >> 5)] = (__bf16)0.f;
    }
    __syncthreads();

    const int wave = tid >> 6, lane = tid & 63;
    const int mrow = qt * 64 + wave * 16 + (lane & 15);
    const int k8 = (lane >> 4) * 8;
    const __bf16* Pr = P + (size_t)bh * NQ_ * 320;

    f32x4 acc0 = (f32x4){0.f, 0.f, 0.f, 0.f};
    f32x4 acc1 = acc0;
#pragma unroll
    for (int k0 = 0; k0 < 320; k0 += 32) {
        bf16x8 aF = {};
        if (mrow < NQ_) aF = *(const bf16x8*)(Pr + (size_t)mrow * 320 + k0 + k8);
        const bf16x8 b0 = *(const bf16x8*)&Vt[lane & 15][k0 + k8];
        const bf16x8 b1 = *(const bf16x8*)&Vt[16 + (lane & 15)][k0 + k8];
        acc0 = __builtin_amdgcn_mfma_f32_16x16x32_bf16(aF, b0, acc0, 0, 0, 0);
        acc1 = __builtin_amdgcn_mfma_f32_16x16x32_bf16(aF, b1, acc1, 0, 0, 0);
    }

    const int row0 = qt * 64 + wave * 16 + (lane >> 4) * 4;
    const int col = lane & 15;
#pragma unroll
    for (int r = 0; r < 4; ++r) {
        if (row0 + r >= NQ_) continue;
        float* op = attn + (size_t)(b * NQ_ + row0 + r) * 256 + h * 32;
        op[col]      = acc0[r];
        op[col + 16] = acc1[r];
    }
}

// ---------------------------------------------------------------------------
__global__ __launch_bounds__(256) void ln_kernel(
    const float* __restrict__ x, const float* __restrict__ res,
    const float* __restrict__ g, const float* __restrict__ bt,
    float* __restrict__ out,
    const float* __restrict__ pos, float* __restrict__ out2)
{
    const int row = blockIdx.x;
    const int tid = threadIdx.x;
    const size_t idx = (size_t)row * D_ + tid;
    float v = x[idx] + (res ? res[idx] : 0.f);

    __shared__ float red[4];
    float s = v;
#pragma unroll
    for (int off = 32; off; off >>= 1) s += __shfl_xor(s, off, 64);
    if ((tid & 63) == 0) red[tid >> 6] = s;
    __syncthreads();
    const float mean = (red[0] + red[1] + red[2] + red[3]) * (1.f / D_);
    const float c = v - mean;
    __syncthreads();

    float s2 = c * c;
#pragma unroll
    for (int off = 32; off; off >>= 1) s2 += __shfl_xor(s2, off, 64);
    if ((tid & 63) == 0) red[tid >> 6] = s2;
    __syncthreads();
    const float var = (red[0] + red[1] + red[2] + red[3]) * (1.f / D_);

    const float y = c * rsqrtf(var + EPS_) * g[tid] + bt[tid];
    out[idx] = y;
    if (out2) out2[idx] = y + pos[idx];
}

// ---------------------------------------------------------------------------
__global__ __launch_bounds__(256) void msdeform_kernel(
    const float* __restrict__ offs, const float* __restrict__ awl,
    const float* __restrict__ refp, const __hip_bfloat16* __restrict__ value,
    float* __restrict__ samp)
{
    const int row = blockIdx.x;
    const int b = row / NQ_;
    const int tid = threadIdx.x;
    const int h = tid >> 5, d = tid & 31;

    __shared__ float off_s[256];
    __shared__ float aw_s[128];
    __shared__ float ref_s[8];
    off_s[tid] = offs[(size_t)row * 256 + tid];
    if (tid < 128) aw_s[tid] = awl[(size_t)row * 128 + tid];
    if (tid < 8) ref_s[tid] = refp[(size_t)row * 8 + tid];
    __syncthreads();

    float mx = -1e30f;
#pragma unroll
    for (int i = 0; i < 16; ++i) mx = fmaxf(mx, aw_s[h * 16 + i]);
    float sum = 0.f;
#pragma unroll
    for (int i = 0; i < 16; ++i) sum += __expf(aw_s[h * 16 + i] - mx);
    const float winv = 1.f / sum;

    const int Hs[4] = {100, 50, 25, 13};
    const int Wl_[4] = {150, 75, 38, 19};
    const int S0[4] = {0, 15000, 18750, 19700};

    float o = 0.f;
    const __hip_bfloat16* vbase = value + ((size_t)b * S_TOT) * D_ + h * 32 + d;

#pragma unroll
    for (int l = 0; l < NL_; ++l) {
        const int Hl = Hs[l], Wl = Wl_[l];
        const float rx = ref_s[l * 2], ry = ref_s[l * 2 + 1];
        const __hip_bfloat16* vl = vbase + (size_t)S0[l] * D_;
#pragma unroll
        for (int p = 0; p < NP_; ++p) {
            const int oi = ((h * NL_ + l) * NP_ + p) * 2;
            const float lx = rx + off_s[oi] / (float)Wl;
            const float ly = ry + off_s[oi + 1] / (float)Hl;
            const float x = lx * Wl - 0.5f;
            const float y = ly * Hl - 0.5f;
            const float x0f = floorf(x), y0f = floorf(y);
            const float tx = x - x0f, ty = y - y0f;
            const int x0 = (int)x0f, y0 = (int)y0f;
            const float aw = __expf(aw_s[h * 16 + l * 4 + p] - mx) * winv;

            float sacc = 0.f;
#pragma unroll
            for (int cc = 0; cc < 4; ++cc) {
                const int dy = cc >> 1, dx = cc & 1;
                const int xi = x0 + dx, yi = y0 + dy;
                const float w = (dy ? ty : 1.f - ty) * (dx ? tx : 1.f - tx);
                if (xi >= 0 && xi < Wl && yi >= 0 && yi < Hl) {
                    const int idx = yi * Wl + xi;
                    sacc += w * __bfloat162float(vl[(size_t)idx * D_]);
                }
            }
            o += aw * sacc;
        }
    }
    samp[(size_t)row * 256 + tid] = o;
}

// ---------------------------------------------------------------------------
extern "C" void kernel_launch(void* const* d_in, const int* in_sizes, int n_in,
                              void* d_out, int out_size, void* d_ws, size_t ws_size,
                              hipStream_t stream)
{
    const float* tgt   = (const float*)d_in[0];
    const float* pos   = (const float*)d_in[1];
    const float* refp  = (const float*)d_in[2];
    const float* memory= (const float*)d_in[3];
    const float* in_w  = (const float*)d_in[7];
    const float* in_b  = (const float*)d_in[8];
    const float* outw  = (const float*)d_in[9];
    const float* outb  = (const float*)d_in[10];
    const float* n1g = (const float*)d_in[11]; const float* n1b = (const float*)d_in[12];
    const float* n2g = (const float*)d_in[13]; const float* n2b = (const float*)d_in[14];
    const float* n3g = (const float*)d_in[15]; const float* n3b = (const float*)d_in[16];
    const float* sow = (const float*)d_in[17]; const float* sob = (const float*)d_in[18];
    const float* aww = (const float*)d_in[19]; const float* awb = (const float*)d_in[20];
    const float* vw  = (const float*)d_in[21]; const float* vb_ = (const float*)d_in[22];
    const float* opw = (const float*)d_in[23]; const float* opb = (const float*)d_in[24];
    const float* l1w = (const float*)d_in[25]; const float* l1b = (const float*)d_in[26];
    const float* l2w = (const float*)d_in[27]; const float* l2b = (const float*)d_in[28];
    float* out = (float*)d_out;

    char* ws = (char*)d_ws;
    size_t o = 0;
    auto alloc = [&](size_t bytes) -> char* {
        char* p = ws + o;
        o += (bytes + 255) & ~(size_t)255;
        return p;
    };

    const int M = BS_ * NQ_;  // 2400
    __bf16* Wb = (__bf16*)alloc((size_t)W_TOT * 2);
    __bf16* Wf = (__bf16*)alloc((size_t)65536 * 2);
    __hip_bfloat16* value = (__hip_bfloat16*)alloc((size_t)BS_ * S_TOT * D_ * 2);
    __bf16* P    = (__bf16*)alloc((size_t)64 * NQ_ * 320 * 2);
    float* qk    = (float*)alloc((size_t)M * 512 * 4);
    float* v     = (float*)alloc((size_t)M * 256 * 4);
    float* attn  = (float*)alloc((size_t)M * 256 * 4);
    float* attno = (float*)alloc((size_t)M * 256 * 4);
    float* tgt1  = (float*)alloc((size_t)M * 256 * 4);
    float* query2= (float*)alloc((size_t)M * 256 * 4);
    float* offs  = (float*)alloc((size_t)M * 256 * 4);
    float* awl   = (float*)alloc((size_t)M * 128 * 4);
    float* samp  = (float*)alloc((size_t)M * 256 * 4);
    float* t2m   = (float*)alloc((size_t)M * 256 * 4);
    float* tgt2  = (float*)alloc((size_t)M * 256 * 4);
    float* ffn1  = (float*)alloc((size_t)M * 1024 * 4);
    float* ffn2  = (float*)alloc((size_t)M * 256 * 4);

    const dim3 blk(256);
    const int MB = (M + 63) / 64;                 // 38
    const int MV32 = (BS_ * S_TOT + 31) / 32;     // 4987

    cast_w_kernel<<<(W_TOT / 4 + 255) / 256, blk, 0, stream>>>(
        in_w, outw, sow, aww, vw, opw, l1w, l2w, Wb);
    rearrange_vw_kernel<<<32, blk, 0, stream>>>(Wb + W_VW, Wf);

    // --- self attention ---
    gemm_small<<<dim3(MB, 8), blk, 0, stream>>>(tgt, pos, Wb + W_INW, in_b, qk, M, 512, 256, 0);
    gemm_small<<<dim3(MB, 4), blk, 0, stream>>>(tgt, nullptr, Wb + W_INW + 512 * 256, in_b + 512, v, M, 256, 256, 0);
    attn_logits_kernel<<<dim3(5, 64), blk, 0, stream>>>(qk, P);
    attn_pv_kernel<<<dim3(5, 64), blk, 0, stream>>>(P, v, attn);
    gemm_small<<<dim3(MB, 4), blk, 0, stream>>>(attn, nullptr, Wb + W_OUTW, outb, attno, M, 256, 256, 0);
    ln_kernel<<<M, blk, 0, stream>>>(tgt, attno, n2g, n2b, tgt1, pos, query2);

    // --- ms-deformable attention ---
    gemm_small<<<dim3(MB, 4), blk, 0, stream>>>(query2, nullptr, Wb + W_SOW, sob, offs, M, 256, 256, 0);
    gemm_small<<<dim3(MB, 2), blk, 0, stream>>>(query2, nullptr, Wb + W_AWW, awb, awl, M, 128, 256, 0);
    gemm_value<<<dim3(MV32), blk, 0, stream>>>(memory, Wf, vb_, value, BS_ * S_TOT);
    msdeform_kernel<<<M, blk, 0, stream>>>(offs, awl, refp, value, samp);
    gemm_small<<<dim3(MB, 4), blk, 0, stream>>>(samp, nullptr, Wb + W_OPW, opb, t2m, M, 256, 256, 0);
    ln_kernel<<<M, blk, 0, stream>>>(tgt1, t2m, n1g, n1b, tgt2, nullptr, nullptr);

    // --- FFN ---
    gemm_small<<<dim3(MB, 16), blk, 0, stream>>>(tgt2, nullptr, Wb + W_L1W, l1b, ffn1, M, 1024, 256, 1);
    gemm_small<<<dim3(MB, 4), blk, 0, stream>>>(ffn1, nullptr, Wb + W_L2W, l2b, ffn2, M, 256, 1024, 0);
    ln_kernel<<<M, blk, 0, stream>>>(tgt2, ffn2, n3g, n3b, out, nullptr, nullptr);
}